// Round 1
// baseline (356.871 us; speedup 1.0000x reference)
//
#include <hip/hip_runtime.h>
#include <hip/hip_bf16.h>
#include <cstdint>

// Problem: B=128, N=512, F_IN=128, F_OUT=128, fp32.
// y = relu(dnorm_n * (adj @ (dnorm_m * x @ W)) + b), dnorm = rsqrt(rowsum(adj))

#define BATCH 128
#define NN    512
#define FIN   128
#define FOUT  128

__device__ __forceinline__ void fma4(float4& c, float a, const float4& b) {
    c.x = fmaf(a, b.x, c.x);
    c.y = fmaf(a, b.y, c.y);
    c.z = fmaf(a, b.z, c.z);
    c.w = fmaf(a, b.w, c.w);
}

// ---------------- K1: dnorm[b*N+n] = rsqrt(sum_m adj[row][m]) ----------------
// one wave per row (512 floats = 128 float4), 4 waves per block
__global__ __launch_bounds__(256) void k_deg(const float* __restrict__ adj,
                                             float* __restrict__ dnorm) {
    int wave = threadIdx.x >> 6;
    int lane = threadIdx.x & 63;
    int row  = (blockIdx.x << 2) + wave;          // [0, B*N)
    const float4* p = (const float4*)(adj + (size_t)row * NN);
    float4 v0 = p[lane];
    float4 v1 = p[lane + 64];
    float s = v0.x + v0.y + v0.z + v0.w + v1.x + v1.y + v1.z + v1.w;
    #pragma unroll
    for (int off = 32; off > 0; off >>= 1) s += __shfl_down(s, off, 64);
    if (lane == 0) dnorm[row] = (s > 0.f) ? rsqrtf(s) : 0.f;
}

// ---------------- K2: h1[r][g] = sum_f (x[r][f]*dnorm[r]) * W[f][g] ----------
// 128-row tile x 128 cols, BK=32, 256 threads, 8x8 micro-tile split 2x2 float4
__global__ __launch_bounds__(256) void k_xw(const float* __restrict__ x,
                                            const float* __restrict__ W,
                                            const float* __restrict__ dnorm,
                                            float* __restrict__ h1) {
    __shared__ float As[32][132];   // A transposed: As[k][m]
    __shared__ float Bs[32][132];   // Bs[k][g]
    int tid  = threadIdx.x;
    int row0 = blockIdx.x * 128;
    int tx = tid & 15, ty = tid >> 4;

    float4 acc[2][2][4];
    #pragma unroll
    for (int p = 0; p < 2; p++)
        #pragma unroll
        for (int q = 0; q < 2; q++)
            #pragma unroll
            for (int i = 0; i < 4; i++) acc[p][q][i] = make_float4(0.f, 0.f, 0.f, 0.f);

    for (int kt = 0; kt < FIN; kt += 32) {
        // stage A = x * dnorm (transposed into LDS)
        #pragma unroll
        for (int j = 0; j < 4; j++) {
            int idx = tid + j * 256;                 // 0..1023
            int m = idx >> 3;                        // 0..127
            int k4 = (idx & 7) << 2;                 // 0,4,...,28
            float4 v = *(const float4*)(x + (size_t)(row0 + m) * FIN + kt + k4);
            float dn = dnorm[row0 + m];
            As[k4 + 0][m] = v.x * dn;
            As[k4 + 1][m] = v.y * dn;
            As[k4 + 2][m] = v.z * dn;
            As[k4 + 3][m] = v.w * dn;
        }
        // stage B = W rows
        #pragma unroll
        for (int j = 0; j < 4; j++) {
            int idx = tid + j * 256;
            int k = idx >> 5;                        // 0..31
            int g4 = (idx & 31) << 2;                // 0..124
            *(float4*)&Bs[k][g4] = *(const float4*)(W + (size_t)(kt + k) * FOUT + g4);
        }
        __syncthreads();
        #pragma unroll 8
        for (int k = 0; k < 32; k++) {
            float4 a0 = *(const float4*)&As[k][ty * 4];
            float4 a1 = *(const float4*)&As[k][ty * 4 + 64];
            float4 b0 = *(const float4*)&Bs[k][tx * 4];
            float4 b1 = *(const float4*)&Bs[k][tx * 4 + 64];
            float ar0[4] = {a0.x, a0.y, a0.z, a0.w};
            float ar1[4] = {a1.x, a1.y, a1.z, a1.w};
            #pragma unroll
            for (int i = 0; i < 4; i++) {
                fma4(acc[0][0][i], ar0[i], b0);
                fma4(acc[0][1][i], ar0[i], b1);
                fma4(acc[1][0][i], ar1[i], b0);
                fma4(acc[1][1][i], ar1[i], b1);
            }
        }
        __syncthreads();
    }
    #pragma unroll
    for (int p = 0; p < 2; p++)
        #pragma unroll
        for (int i = 0; i < 4; i++) {
            int row = row0 + ty * 4 + p * 64 + i;
            #pragma unroll
            for (int q = 0; q < 2; q++)
                *(float4*)(h1 + (size_t)row * FOUT + tx * 4 + q * 64) = acc[p][q][i];
        }
}

// ---------------- K3: out = relu(dnorm_n * (adj @ h1) + bias) ---------------
// per batch: 512x512 @ 512x128; block = 128-row tile x 128 cols, BK=32
__global__ __launch_bounds__(256) void k_agg(const float* __restrict__ adj,
                                             const float* __restrict__ h1,
                                             const float* __restrict__ dnorm,
                                             const float* __restrict__ bias,
                                             float* __restrict__ out) {
    __shared__ float As[32][132];   // adj tile transposed: As[k][n]
    __shared__ float Bs[32][132];   // h1 tile: Bs[k][g]
    int tid = threadIdx.x;
    int b   = blockIdx.y;
    int n0  = blockIdx.x * 128;
    const float* A  = adj + (size_t)b * NN * NN;
    const float* Bm = h1 + (size_t)b * NN * FOUT;
    int tx = tid & 15, ty = tid >> 4;

    float4 acc[2][2][4];
    #pragma unroll
    for (int p = 0; p < 2; p++)
        #pragma unroll
        for (int q = 0; q < 2; q++)
            #pragma unroll
            for (int i = 0; i < 4; i++) acc[p][q][i] = make_float4(0.f, 0.f, 0.f, 0.f);

    for (int kt = 0; kt < NN; kt += 32) {
        #pragma unroll
        for (int j = 0; j < 4; j++) {
            int idx = tid + j * 256;
            int m = idx >> 3;                        // row within tile 0..127
            int k4 = (idx & 7) << 2;
            float4 v = *(const float4*)(A + (size_t)(n0 + m) * NN + kt + k4);
            As[k4 + 0][m] = v.x;
            As[k4 + 1][m] = v.y;
            As[k4 + 2][m] = v.z;
            As[k4 + 3][m] = v.w;
        }
        #pragma unroll
        for (int j = 0; j < 4; j++) {
            int idx = tid + j * 256;
            int k = idx >> 5;
            int g4 = (idx & 31) << 2;
            *(float4*)&Bs[k][g4] = *(const float4*)(Bm + (size_t)(kt + k) * FOUT + g4);
        }
        __syncthreads();
        #pragma unroll 8
        for (int k = 0; k < 32; k++) {
            float4 a0 = *(const float4*)&As[k][ty * 4];
            float4 a1 = *(const float4*)&As[k][ty * 4 + 64];
            float4 b0 = *(const float4*)&Bs[k][tx * 4];
            float4 b1 = *(const float4*)&Bs[k][tx * 4 + 64];
            float ar0[4] = {a0.x, a0.y, a0.z, a0.w};
            float ar1[4] = {a1.x, a1.y, a1.z, a1.w};
            #pragma unroll
            for (int i = 0; i < 4; i++) {
                fma4(acc[0][0][i], ar0[i], b0);
                fma4(acc[0][1][i], ar0[i], b1);
                fma4(acc[1][0][i], ar1[i], b0);
                fma4(acc[1][1][i], ar1[i], b1);
            }
        }
        __syncthreads();
    }

    float4 bias0 = *(const float4*)(bias + tx * 4);
    float4 bias1 = *(const float4*)(bias + tx * 4 + 64);
    #pragma unroll
    for (int p = 0; p < 2; p++)
        #pragma unroll
        for (int i = 0; i < 4; i++) {
            int row = n0 + ty * 4 + p * 64 + i;
            float dn = dnorm[(size_t)b * NN + row];
            float4 c0 = acc[p][0][i];
            float4 c1 = acc[p][1][i];
            c0.x = fmaxf(fmaf(c0.x, dn, bias0.x), 0.f);
            c0.y = fmaxf(fmaf(c0.y, dn, bias0.y), 0.f);
            c0.z = fmaxf(fmaf(c0.z, dn, bias0.z), 0.f);
            c0.w = fmaxf(fmaf(c0.w, dn, bias0.w), 0.f);
            c1.x = fmaxf(fmaf(c1.x, dn, bias1.x), 0.f);
            c1.y = fmaxf(fmaf(c1.y, dn, bias1.y), 0.f);
            c1.z = fmaxf(fmaf(c1.z, dn, bias1.z), 0.f);
            c1.w = fmaxf(fmaf(c1.w, dn, bias1.w), 0.f);
            float* o = out + ((size_t)b * NN + row) * FOUT + tx * 4;
            *(float4*)o = c0;
            *(float4*)(o + 64) = c1;
        }
}

extern "C" void kernel_launch(void* const* d_in, const int* in_sizes, int n_in,
                              void* d_out, int out_size, void* d_ws, size_t ws_size,
                              hipStream_t stream) {
    const float* adj  = (const float*)d_in[0];
    const float* x    = (const float*)d_in[1];
    const float* W    = (const float*)d_in[2];
    const float* bias = (const float*)d_in[3];
    float* out = (float*)d_out;

    float* dnorm = (float*)d_ws;                       // B*N floats
    float* h1    = dnorm + (size_t)BATCH * NN;         // B*N*FOUT floats

    hipLaunchKernelGGL(k_deg, dim3(BATCH * NN / 4), dim3(256), 0, stream, adj, dnorm);
    hipLaunchKernelGGL(k_xw,  dim3(BATCH * NN / 128), dim3(256), 0, stream, x, W, dnorm, h1);
    hipLaunchKernelGGL(k_agg, dim3(4, BATCH), dim3(256), 0, stream, adj, h1, dnorm, bias, out);
}

// Round 3
// 263.315 us; speedup vs baseline: 1.3553x; 1.3553x over previous
//
#include <hip/hip_runtime.h>
#include <hip/hip_bf16.h>
#include <cstdint>

// GCN layer: y = relu(dnorm_n * (adj @ (dnorm_m * x @ W)) + b)
// B=128, N=512, F_IN=F_OUT=128, fp32 in/out. bf16 MFMA internally.

#define BATCH 128
#define NN    512
#define FIN   128
#define FOUT  128

typedef unsigned short u16;
typedef __attribute__((ext_vector_type(8))) __bf16 bfrag;   // 8 bf16 = 4 VGPRs
typedef __attribute__((ext_vector_type(4))) float  f32x4;

__device__ __forceinline__ u16 f2bf(float f) {
    uint32_t u = __builtin_bit_cast(uint32_t, f);
    u += 0x7fffu + ((u >> 16) & 1u);          // round-nearest-even
    return (u16)(u >> 16);
}
__device__ __forceinline__ ushort4 f2bf4(float4 v) {
    ushort4 r;
    r.x = f2bf(v.x); r.y = f2bf(v.y); r.z = f2bf(v.z); r.w = f2bf(v.w);
    return r;
}

// ---------------- k_prep: Wt[g][k] = bf16(W[k][g]) --------------------------
__global__ __launch_bounds__(256) void k_prep(const float* __restrict__ W,
                                              u16* __restrict__ Wt) {
    int idx = blockIdx.x * 256 + threadIdx.x;   // grid 64 -> 16384 elements
    int g = idx >> 7, k = idx & 127;
    Wt[idx] = f2bf(W[k * FOUT + g]);
}

// ---------------- k_deg: dnorm[row] = rsqrt(rowsum(adj)) --------------------
__global__ __launch_bounds__(256) void k_deg(const float* __restrict__ adj,
                                             float* __restrict__ dnorm) {
    int wave = threadIdx.x >> 6;
    int lane = threadIdx.x & 63;
    int row  = (blockIdx.x << 2) + wave;          // [0, B*N)
    const float4* p = (const float4*)(adj + (size_t)row * NN);
    float4 v0 = p[lane];
    float4 v1 = p[lane + 64];
    float s = v0.x + v0.y + v0.z + v0.w + v1.x + v1.y + v1.z + v1.w;
    #pragma unroll
    for (int off = 32; off > 0; off >>= 1) s += __shfl_down(s, off, 64);
    if (lane == 0) dnorm[row] = (s > 0.f) ? rsqrtf(s) : 0.f;
}

// ---------------- k_xw: h1t[b][g][m] = bf16(dnorm[bm] * (x @ W)[bm][g]) -----
// 128-row tile x 128 cols; 4 waves, each 4x4 grid of 16x16x32 bf16 MFMA
__global__ __launch_bounds__(256) void k_xw(const float* __restrict__ x,
                                            const u16* __restrict__ Wt,
                                            const float* __restrict__ dnorm,
                                            u16* __restrict__ h1t) {
    __shared__ u16 As[128][40];   // As[m][k] bf16, row pad to 40 (80 B)
    __shared__ u16 Bs[128][40];   // Bs[g][k] bf16 (Wt is already [g][k])
    __shared__ float sDn[128];

    int tid  = threadIdx.x;
    int row0 = blockIdx.x * 128;                 // global node-row base
    int wave = tid >> 6, lane = tid & 63;
    int wr = wave >> 1, wc = wave & 1;
    int q = lane >> 4, l16 = lane & 15;

    if (tid < 128) sDn[tid] = dnorm[row0 + tid];

    f32x4 acc[4][4];
    #pragma unroll
    for (int i = 0; i < 4; i++)
        #pragma unroll
        for (int j = 0; j < 4; j++) acc[i][j] = (f32x4)(0.f);

    for (int kt = 0; kt < FIN; kt += 32) {
        // stage A: x fp32 -> bf16 (128 m-rows x 32 k)
        #pragma unroll
        for (int j = 0; j < 4; j++) {
            int linear = tid + j * 256;          // 0..1023 float4 slots
            int m = linear >> 3, k4 = (linear & 7) << 2;
            float4 v = *(const float4*)(x + (size_t)(row0 + m) * FIN + kt + k4);
            *(ushort4*)&As[m][k4] = f2bf4(v);
        }
        // stage B: Wt bf16, 128 g-rows x 32 k = 512 uint4 slots (4 per row)
        #pragma unroll
        for (int j = 0; j < 2; j++) {
            int linear = tid + j * 256;          // 0..511
            int g = linear >> 2, k8 = (linear & 3) << 3;
            *(uint4*)&Bs[g][k8] = *(const uint4*)(Wt + (size_t)g * FIN + kt + k8);
        }
        __syncthreads();
        bfrag aF[4], bF[4];
        #pragma unroll
        for (int i = 0; i < 4; i++) aF[i] = *(const bfrag*)&As[wr * 64 + i * 16 + l16][q * 8];
        #pragma unroll
        for (int j = 0; j < 4; j++) bF[j] = *(const bfrag*)&Bs[wc * 64 + j * 16 + l16][q * 8];
        #pragma unroll
        for (int i = 0; i < 4; i++)
            #pragma unroll
            for (int j = 0; j < 4; j++)
                acc[i][j] = __builtin_amdgcn_mfma_f32_16x16x32_bf16(aF[i], bF[j], acc[i][j], 0, 0, 0);
        __syncthreads();
    }

    // epilogue: scale rows by dnorm, store transposed bf16
    int bb = row0 >> 9;                  // batch
    int mb = row0 & 511;                 // node base within batch
    #pragma unroll
    for (int i = 0; i < 4; i++) {
        int mloc = wr * 64 + i * 16 + q * 4;
        float d0 = sDn[mloc], d1 = sDn[mloc + 1], d2 = sDn[mloc + 2], d3 = sDn[mloc + 3];
        #pragma unroll
        for (int j = 0; j < 4; j++) {
            int g = wc * 64 + j * 16 + l16;
            f32x4 c = acc[i][j];
            ushort4 v;
            v.x = f2bf(c[0] * d0); v.y = f2bf(c[1] * d1);
            v.z = f2bf(c[2] * d2); v.w = f2bf(c[3] * d3);
            *(ushort4*)(h1t + ((size_t)bb * FOUT + g) * NN + mb + mloc) = v;
        }
    }
}

// ---------------- k_agg: out = relu(dnorm_n * (adj @ h1) + bias) ------------
// per batch 512x128; block = 128 rows x 128 cols, K=512 in BK=32 steps
__global__ __launch_bounds__(256) void k_agg(const float* __restrict__ adj,
                                             const u16* __restrict__ h1t,
                                             const float* __restrict__ dnorm,
                                             const float* __restrict__ bias,
                                             float* __restrict__ out) {
    __shared__ u16 As[128][40];   // As[n][k] = bf16(adj[n0+n][kt+k])
    __shared__ u16 Bs[128][40];   // Bs[g][k] = h1t[b][g][kt+k]
    __shared__ float sDn[128];
    __shared__ float sBias[128];

    int tid = threadIdx.x;
    int b   = blockIdx.y;
    int n0  = blockIdx.x * 128;
    int wave = tid >> 6, lane = tid & 63;
    int wr = wave >> 1, wc = wave & 1;
    int q = lane >> 4, l16 = lane & 15;

    const float* A   = adj + (size_t)b * NN * NN;
    const u16*   Bm  = h1t + (size_t)b * FOUT * NN;
    if (tid < 128) { sDn[tid] = dnorm[(size_t)b * NN + n0 + tid]; sBias[tid] = bias[tid]; }

    f32x4 acc[4][4];
    #pragma unroll
    for (int i = 0; i < 4; i++)
        #pragma unroll
        for (int j = 0; j < 4; j++) acc[i][j] = (f32x4)(0.f);

    for (int kt = 0; kt < NN; kt += 32) {
        // stage A: adj fp32 -> bf16 (128 rows x 32 k)
        #pragma unroll
        for (int j = 0; j < 4; j++) {
            int linear = tid + j * 256;
            int m = linear >> 3, k4 = (linear & 7) << 2;
            float4 v = *(const float4*)(A + (size_t)(n0 + m) * NN + kt + k4);
            *(ushort4*)&As[m][k4] = f2bf4(v);
        }
        // stage B: h1t bf16, 128 g x 32 k (4 uint4 slots per g)
        #pragma unroll
        for (int j = 0; j < 2; j++) {
            int linear = tid + j * 256;          // 0..511 slots of 16 B
            int g = linear >> 2, k8 = (linear & 3) << 3;
            *(uint4*)&Bs[g][k8] = *(const uint4*)(Bm + (size_t)g * NN + kt + k8);
        }
        __syncthreads();
        bfrag aF[4], bF[4];
        #pragma unroll
        for (int i = 0; i < 4; i++) aF[i] = *(const bfrag*)&As[wr * 64 + i * 16 + l16][q * 8];
        #pragma unroll
        for (int j = 0; j < 4; j++) bF[j] = *(const bfrag*)&Bs[wc * 64 + j * 16 + l16][q * 8];
        #pragma unroll
        for (int i = 0; i < 4; i++)
            #pragma unroll
            for (int j = 0; j < 4; j++)
                acc[i][j] = __builtin_amdgcn_mfma_f32_16x16x32_bf16(aF[i], bF[j], acc[i][j], 0, 0, 0);
        __syncthreads();
    }

    // epilogue: dnorm_n scale + bias + relu, fp32 store
    #pragma unroll
    for (int i = 0; i < 4; i++) {
        int rloc = wr * 64 + i * 16 + q * 4;
        float d0 = sDn[rloc], d1 = sDn[rloc + 1], d2 = sDn[rloc + 2], d3 = sDn[rloc + 3];
        #pragma unroll
        for (int j = 0; j < 4; j++) {
            int col = wc * 64 + j * 16 + l16;
            float bsv = sBias[col];
            f32x4 c = acc[i][j];
            float* o = out + ((size_t)b * NN + n0 + rloc) * FOUT + col;
            o[0 * FOUT] = fmaxf(fmaf(c[0], d0, bsv), 0.f);
            o[1 * FOUT] = fmaxf(fmaf(c[1], d1, bsv), 0.f);
            o[2 * FOUT] = fmaxf(fmaf(c[2], d2, bsv), 0.f);
            o[3 * FOUT] = fmaxf(fmaf(c[3], d3, bsv), 0.f);
        }
    }
}

extern "C" void kernel_launch(void* const* d_in, const int* in_sizes, int n_in,
                              void* d_out, int out_size, void* d_ws, size_t ws_size,
                              hipStream_t stream) {
    const float* adj  = (const float*)d_in[0];
    const float* x    = (const float*)d_in[1];
    const float* W    = (const float*)d_in[2];
    const float* bias = (const float*)d_in[3];
    float* out = (float*)d_out;

    char* ws = (char*)d_ws;
    float* dnorm = (float*)ws;                                   // 65536 f32 = 256 KB
    u16*   Wt    = (u16*)(ws + 262144);                          // 16384 bf16 = 32 KB
    u16*   h1t   = (u16*)(ws + 262144 + 32768);                  // 8.4M bf16 = 16.8 MB

    hipLaunchKernelGGL(k_prep, dim3(64), dim3(256), 0, stream, W, Wt);
    hipLaunchKernelGGL(k_deg,  dim3(BATCH * NN / 4), dim3(256), 0, stream, adj, dnorm);
    hipLaunchKernelGGL(k_xw,   dim3(BATCH * NN / 128), dim3(256), 0, stream, x, Wt, dnorm, h1t);
    hipLaunchKernelGGL(k_agg,  dim3(4, BATCH), dim3(256), 0, stream, adj, h1t, dnorm, bias, out);
}